// Round 1
// 307.927 us; speedup vs baseline: 1.0192x; 1.0192x over previous
//
#include <hip/hip_runtime.h>
#include <hip/hip_bf16.h>

typedef __hip_bfloat16 bf16;
typedef __attribute__((ext_vector_type(8))) short short8;
typedef __attribute__((ext_vector_type(4))) float float4v;

#define Hd 256
#define Wd 256
#define HW 65536
#define CO 64

// ---------------------------------------------------------------------------
// K1: style MLP + modulated/demodulated weights. One block per (o, s).
// wA layout: [s][kc(18)][o(64)][32], k = tap*64 + i (tap-major).
// ---------------------------------------------------------------------------
__global__ __launch_bounds__(64) void k1_style(
    const float* __restrict__ vec, const float* __restrict__ w1,
    const float* __restrict__ w2, const float* __restrict__ wconv,
    bf16* __restrict__ wA)
{
    int o = blockIdx.x;      // 0..63
    int s = blockIdx.y;      // 0..7
    int i = threadIdx.x;     // lane = input channel

    float sv[4];
#pragma unroll
    for (int q = 0; q < 4; ++q) sv[q] = vec[s * 256 + q * 64 + i];

    float hid[16];
#pragma unroll
    for (int j = 0; j < 16; ++j) {
        float p = 0.f;
#pragma unroll
        for (int q = 0; q < 4; ++q) p += sv[q] * w1[j * 256 + q * 64 + i];
#pragma unroll
        for (int off = 32; off >= 1; off >>= 1) p += __shfl_xor(p, off, 64);
        hid[j] = p > 0.f ? p : 0.1f * p;   // LeakyReLU(0.1)
    }
    float sty = 0.f;
#pragma unroll
    for (int j = 0; j < 16; ++j) sty += w2[i * 16 + j] * hid[j];
    float msty = sty + 1.0f;               // per input-channel i

    float wrow[9];
#pragma unroll
    for (int tt = 0; tt < 9; ++tt) wrow[tt] = wconv[(o * 64 + i) * 9 + tt] * msty;
    float ss = 0.f;
#pragma unroll
    for (int tt = 0; tt < 9; ++tt) ss += wrow[tt] * wrow[tt];
#pragma unroll
    for (int off = 32; off >= 1; off >>= 1) ss += __shfl_xor(ss, off, 64);
    float d = rsqrtf(ss + 1e-8f);

    bf16* wAs = wA + s * (18 * 64 * 32);
#pragma unroll
    for (int tt = 0; tt < 9; ++tt) {
        int k = tt * 64 + i;
        wAs[(k >> 5) * 2048 + o * 32 + (k & 31)] = (bf16)(wrow[tt] * d);
    }
}

// ---------------------------------------------------------------------------
// K3: FUSED ChanNorm + implicit-GEMM 3x3 conv + residual.
// Block = (s, 8 output rows, 32-px strip). Stage 10 halo rows x 34 px:
// per-thread per-pixel channel-norm (fp32 x -> bf16), ONE barrier, then
// 8 rows of barrier-free ds_read+MFMA+epilogue.
// Tile layout: [row(10)][c8(8)][wl(34)][8] bf16; ch8 stride 544B == 32 mod 128.
// Waves 2x2: wave = 32 o (2 mt, A-frags resident in VGPRs) x 16 px.
// Residual: NOT re-read from HBM (was 128 MB of L2-cold fetch + a per-row
// scattered-gather latency chain). Instead staging stashes per-pixel
// (mean, std) in LDS and the epilogue reconstructs
//   x = (nx - b[o]) * (1/g[o]) * std + mean
// from the bf16 tile. Costs 1 ds_read_u16 + 1 ds_read_b64 + ~3 VALU per
// output element; adds <= bf16_eps*|nx|*std ~ 0.01 absolute error.
// ---------------------------------------------------------------------------
#define PXB 32
#define ROWS 8
#define TR 10
#define WL 34
#define ROW_ELEMS (8 * WL * 8)   // 2176 elems = 4352 B; 10 rows = 43520 B

__global__ __launch_bounds__(256, 2) void k3_fused(
    const float* __restrict__ x, const float* __restrict__ gg,
    const float* __restrict__ bb, const bf16* __restrict__ wA,
    float* __restrict__ out)
{
    int w0 = blockIdx.x * PXB;   // 0..7 -> 0..224
    int h0 = blockIdx.y * ROWS;  // 0..31 -> 0..248
    int s  = blockIdx.z;
    int t  = threadIdx.x;
    __shared__ __align__(16) bf16 tile[TR * ROW_ELEMS];
    __shared__ float sg[64], sb[64];
    __shared__ float2 sbi[64];           // {b[o], 1/g[o]} for reconstruction
    __shared__ float2 sms[TR * WL];      // {mean, std} per staged pixel site
    if (t < 64) {
        float gv = gg[t];
        sg[t] = gv; sb[t] = bb[t];
        sbi[t] = make_float2(bb[t], 1.0f / gv);
    }
    __syncthreads();

    // ---- stage + fused ChanNorm: 340 (row,px) sites, thread-per-pixel ----
    for (int p = t; p < TR * WL; p += 256) {
        int dr = p / WL, wl = p - dr * WL;
        int grow = h0 + dr - 1, wabs = w0 + wl - 1;
        bf16* dst = &tile[dr * ROW_ELEMS + wl * 8];
        if (grow >= 0 && grow < Hd && wabs >= 0 && wabs < Wd) {
            const float* xp = x + (size_t)s * (CO * HW) + (size_t)grow * Wd + wabs;
            float v[64], s1 = 0.f, s2 = 0.f;
#pragma unroll
            for (int c = 0; c < 64; ++c) {
                float f = xp[(size_t)c * HW];
                v[c] = f; s1 += f; s2 += f * f;
            }
            float mean = s1 * (1.f / 64);
            float var  = s2 * (1.f / 64) - mean * mean;
            float rstd = rsqrtf(var + 1e-5f);
            sms[p] = make_float2(mean, sqrtf(var + 1e-5f));
#pragma unroll
            for (int c8 = 0; c8 < 8; ++c8) {
                bf16 ov[8];
#pragma unroll
                for (int k = 0; k < 8; ++k) {
                    int c = c8 * 8 + k;
                    ov[k] = (bf16)((v[c] - mean) * rstd * sg[c] + sb[c]);
                }
                *(uint4*)&dst[c8 * (WL * 8)] = *(uint4*)ov;
            }
        } else {
            sms[p] = make_float2(0.f, 0.f);
            uint4 z = make_uint4(0u, 0u, 0u, 0u);
#pragma unroll
            for (int c8 = 0; c8 < 8; ++c8) *(uint4*)&dst[c8 * (WL * 8)] = z;
        }
    }
    __syncthreads();   // the ONLY compute barrier

    int wave = t >> 6, lane = t & 63;
    int mi = wave & 1, ni = wave >> 1;   // wave tile: o in [mi*32,+32), px in [ni*16,+16)
    int col = lane & 15, quad = lane >> 4;

    // preload A fragments: 18 kc x 2 mt, resident across all 8 rows
    const bf16* wAs = wA + s * (18 * 64 * 32);
    short8 afrag[18][2];
#pragma unroll
    for (int kc = 0; kc < 18; ++kc)
#pragma unroll
        for (int mt = 0; mt < 2; ++mt) {
            union { uint4 u; short8 s8; } a;
            a.u = *(const uint4*)&wAs[kc * 2048 + (mi * 32 + mt * 16 + col) * 32 + quad * 8];
            afrag[kc][mt] = a.s8;
        }

    int wl_i = ni * 16 + col + 1;        // interior staged column for this lane

#pragma unroll 2
    for (int r = 0; r < ROWS; ++r) {
        float4v acc[2];
        acc[0] = (float4v)0.f; acc[1] = (float4v)0.f;
#pragma unroll
        for (int kc = 0; kc < 18; ++kc) {
            int tap = kc >> 1;
            int kh = tap / 3, kw = tap - kh * 3;
            int ch8 = (kc & 1) * 4 + quad;
            int wl = ni * 16 + col + kw;          // <= 33
            union { uint4 u; short8 s8; } b;
            b.u = *(const uint4*)&tile[(r + kh) * ROW_ELEMS + (ch8 * WL + wl) * 8];
            acc[0] = __builtin_amdgcn_mfma_f32_16x16x32_bf16(afrag[kc][0], b.s8, acc[0], 0, 0, 0);
            acc[1] = __builtin_amdgcn_mfma_f32_16x16x32_bf16(afrag[kc][1], b.s8, acc[1], 0, 0, 0);
        }
        // epilogue: residual reconstructed from LDS (no HBM re-read)
        int grow = h0 + r;
        int wpx  = w0 + ni * 16 + col;
        float2 ms = sms[(r + 1) * WL + wl_i];     // {mean, std} of this pixel
#pragma unroll
        for (int mt = 0; mt < 2; ++mt) {
#pragma unroll
            for (int rr = 0; rr < 4; ++rr) {
                int o = mi * 32 + mt * 16 + quad * 4 + rr;
                float nxf = __bfloat162float(
                    tile[(r + 1) * ROW_ELEMS + ((o >> 3) * WL + wl_i) * 8 + (o & 7)]);
                float2 bi = sbi[o];
                float xrec = (nxf - bi.x) * bi.y * ms.y + ms.x;
                size_t idx = (size_t)(s * CO + o) * HW + (size_t)grow * Wd + wpx;
                out[idx] = acc[mt][rr] + xrec;
            }
        }
    }
}

extern "C" void kernel_launch(void* const* d_in, const int* in_sizes, int n_in,
                              void* d_out, int out_size, void* d_ws, size_t ws_size,
                              hipStream_t stream)
{
    const float* x     = (const float*)d_in[0];
    const float* vec   = (const float*)d_in[1];
    const float* g     = (const float*)d_in[2];
    const float* bb    = (const float*)d_in[3];
    const float* w1    = (const float*)d_in[4];
    const float* w2    = (const float*)d_in[5];
    const float* wconv = (const float*)d_in[6];
    float* out = (float*)d_out;

    bf16* wA = (bf16*)d_ws;    // 8*18*64*32 bf16 = 576 KB

    k1_style<<<dim3(64, 8), 64, 0, stream>>>(vec, w1, w2, wconv, wA);
    k3_fused<<<dim3(8, 32, 8), 256, 0, stream>>>(x, g, bb, wA, out);
}